// Round 9
// baseline (245.789 us; speedup 1.0000x reference)
//
#include <hip/hip_runtime.h>

typedef __bf16 bf16_t;
typedef __bf16 bf16x4 __attribute__((ext_vector_type(4)));
typedef __bf16 bf16x8 __attribute__((ext_vector_type(8)));
typedef float f32x4 __attribute__((ext_vector_type(4)));
typedef short short4v __attribute__((ext_vector_type(4)));

#define E_DIM 1024
#define S_LEN 1024
#define NHEAD 16
#define HD_DIM 64
#define BATCH 4
#define TOKENS 4096

// ---------------------------------------------------------------- helpers
__device__ __forceinline__ void async_copy16(const bf16_t* g, bf16_t* l) {
    __builtin_amdgcn_global_load_lds((const __attribute__((address_space(1))) void*)g,
                                     (__attribute__((address_space(3))) void*)l,
                                     16, 0, 0);
}

__device__ __forceinline__ bf16x8 cvt8(const float* src) {
    float4 x = *(const float4*)src;
    float4 y = *(const float4*)(src + 4);
    bf16x8 o;
    o[0] = (bf16_t)x.x; o[1] = (bf16_t)x.y; o[2] = (bf16_t)x.z; o[3] = (bf16_t)x.w;
    o[4] = (bf16_t)y.x; o[5] = (bf16_t)y.y; o[6] = (bf16_t)y.z; o[7] = (bf16_t)y.w;
    return o;
}

// PV matmul: 16x16x16 bf16 MFMA (k = quad*4+i matches 16x16 C/D row layout).
__device__ __forceinline__ f32x4 pv_mfma(bf16x4 a, bf16x4 b, f32x4 c) {
#if __has_builtin(__builtin_amdgcn_mfma_f32_16x16x16_bf16)
    return __builtin_amdgcn_mfma_f32_16x16x16_bf16(a, b, c, 0, 0, 0);
#elif __has_builtin(__builtin_amdgcn_mfma_f32_16x16x16bf16_1k)
    short4v as, bs;
    __builtin_memcpy(&as, &a, 8);
    __builtin_memcpy(&bs, &b, 8);
    return __builtin_amdgcn_mfma_f32_16x16x16bf16_1k(as, bs, c, 0, 0, 0);
#else
    f32x4 d;
    asm volatile("v_mfma_f32_16x16x16_bf16 %0, %1, %2, %3\n\ts_nop 7\n\ts_nop 7"
                 : "=v"(d)
                 : "v"(a), "v"(b), "v"(c));
    return d;
#endif
}

// ---------------------------------------------------------------- batched projection GEMM
// fp32 inputs, cast fused into staging (float4x2 -> cvt -> ds_write_b128; 2 lanes/word = free).
// 128x128 tile, BK=32, 16 mfma/wave/iter, XCD swizzle (R7/R8-proven mapping).
__global__ __launch_bounds__(256, 4) void proj_gemm(const float* __restrict__ Xq,
                                                    const float* __restrict__ Xk,
                                                    const float* __restrict__ Xv,
                                                    const float* __restrict__ Wq,
                                                    const float* __restrict__ Wk,
                                                    const float* __restrict__ Wv,
                                                    bf16_t* __restrict__ Qp,
                                                    bf16_t* __restrict__ Kp,
                                                    bf16_t* __restrict__ Vp) {
    __shared__ bf16_t sA[128 * 32];
    __shared__ bf16_t sB[128 * 32];
    const int z = blockIdx.z;
    const float* A = z == 0 ? Xq : (z == 1 ? Xk : Xv);
    const float* B = z == 0 ? Wq : (z == 1 ? Wk : Wv);
    bf16_t* C = z == 0 ? Qp : (z == 1 ? Kp : Vp);
    const int N = 1024, K = 1024;
    const int lid = blockIdx.x + 8 * blockIdx.y;
    const int m0 = (((lid & 7) << 2) + ((lid >> 3) & 3)) * 128;
    const int n0 = (lid >> 5) * 128;

    const int tid = threadIdx.x;
    const int wave = tid >> 6, lane = tid & 63;
    const int quad = lane >> 4, l16 = lane & 15;
    const int wm = (wave >> 1) * 64, wn = (wave & 1) * 64;
    const int srow = lane >> 2, scol = (lane & 3) * 8;

    f32x4 acc[4][4];
    const f32x4 vzero = {0.f, 0.f, 0.f, 0.f};
#pragma unroll
    for (int mt = 0; mt < 4; mt++)
#pragma unroll
        for (int nt = 0; nt < 4; nt++) acc[mt][nt] = vzero;

    for (int k0 = 0; k0 < K; k0 += 32) {
        __syncthreads();
        // 16 chunks of 16 rows x 32 cols; 4 per wave; fp32 load + cvt + b128 LDS write
#pragma unroll
        for (int cc = 0; cc < 4; cc++) {
            int c = wave * 4 + cc;
            const float* g;
            bf16_t* l;
            if (c < 8) {
                g = A + (size_t)(m0 + c * 16 + srow) * K + k0 + scol;
                l = &sA[c * 512 + srow * 32 + scol];
            } else {
                g = B + (size_t)(n0 + (c - 8) * 16 + srow) * K + k0 + scol;
                l = &sB[(c - 8) * 512 + srow * 32 + scol];
            }
            *(bf16x8*)l = cvt8(g);
        }
        __syncthreads();

        bf16x8 af[4], bfr[4];
#pragma unroll
        for (int mt = 0; mt < 4; mt++)
            af[mt] = *(const bf16x8*)&sA[(wm + mt * 16 + l16) * 32 + quad * 8];
#pragma unroll
        for (int nt = 0; nt < 4; nt++)
            bfr[nt] = *(const bf16x8*)&sB[(wn + nt * 16 + l16) * 32 + quad * 8];
#pragma unroll
        for (int mt = 0; mt < 4; mt++)
#pragma unroll
            for (int nt = 0; nt < 4; nt++)
                acc[mt][nt] = __builtin_amdgcn_mfma_f32_16x16x32_bf16(af[mt], bfr[nt],
                                                                      acc[mt][nt], 0, 0, 0);
    }

#pragma unroll
    for (int mt = 0; mt < 4; mt++)
#pragma unroll
        for (int nt = 0; nt < 4; nt++)
#pragma unroll
            for (int r = 0; r < 4; r++) {
                int row = m0 + wm + mt * 16 + quad * 4 + r;
                int col = n0 + wn + nt * 16 + l16;
                C[(size_t)row * N + col] = (bf16_t)acc[mt][nt][r];
            }
}

// ---------------------------------------------------------------- output GEMM
// A = ctx (bf16, global_load_lds); B = Wo (fp32, fused-cast staging); fp32 out.
__global__ __launch_bounds__(256, 4) void out_gemm(const bf16_t* __restrict__ A,
                                                   const float* __restrict__ B,
                                                   float* __restrict__ C) {
    __shared__ bf16_t sA[128 * 32];
    __shared__ bf16_t sB[128 * 32];
    const int N = 1024, K = 1024;
    const int lid = blockIdx.x + 8 * blockIdx.y;
    const int m0 = (((lid & 7) << 2) + ((lid >> 3) & 3)) * 128;
    const int n0 = (lid >> 5) * 128;

    const int tid = threadIdx.x;
    const int wave = tid >> 6, lane = tid & 63;
    const int quad = lane >> 4, l16 = lane & 15;
    const int wm = (wave >> 1) * 64, wn = (wave & 1) * 64;
    const int srow = lane >> 2, scol = (lane & 3) * 8;

    f32x4 acc[4][4];
    const f32x4 vzero = {0.f, 0.f, 0.f, 0.f};
#pragma unroll
    for (int mt = 0; mt < 4; mt++)
#pragma unroll
        for (int nt = 0; nt < 4; nt++) acc[mt][nt] = vzero;

    for (int k0 = 0; k0 < K; k0 += 32) {
        __syncthreads();
#pragma unroll
        for (int cc = 0; cc < 4; cc++) {
            int c = wave * 4 + cc;
            if (c < 8) {
                const bf16_t* g = A + (size_t)(m0 + c * 16 + srow) * K + k0 + scol;
                async_copy16(g, &sA[c * 512]);
            } else {
                const float* g = B + (size_t)(n0 + (c - 8) * 16 + srow) * K + k0 + scol;
                *(bf16x8*)&sB[(c - 8) * 512 + srow * 32 + scol] = cvt8(g);
            }
        }
        asm volatile("s_waitcnt vmcnt(0)" ::: "memory");
        __syncthreads();

        bf16x8 af[4], bfr[4];
#pragma unroll
        for (int mt = 0; mt < 4; mt++)
            af[mt] = *(const bf16x8*)&sA[(wm + mt * 16 + l16) * 32 + quad * 8];
#pragma unroll
        for (int nt = 0; nt < 4; nt++)
            bfr[nt] = *(const bf16x8*)&sB[(wn + nt * 16 + l16) * 32 + quad * 8];
#pragma unroll
        for (int mt = 0; mt < 4; mt++)
#pragma unroll
            for (int nt = 0; nt < 4; nt++)
                acc[mt][nt] = __builtin_amdgcn_mfma_f32_16x16x32_bf16(af[mt], bfr[nt],
                                                                      acc[mt][nt], 0, 0, 0);
    }

#pragma unroll
    for (int mt = 0; mt < 4; mt++)
#pragma unroll
        for (int nt = 0; nt < 4; nt++)
#pragma unroll
            for (int r = 0; r < 4; r++) {
                int row = m0 + wm + mt * 16 + quad * 4 + r;
                int col = n0 + wn + nt * 16 + l16;
                C[(size_t)row * N + col] = acc[mt][nt][r];
            }
}

// ---------------------------------------------------------------- flash attention v4 (R8-proven)
#define KP 72

__global__ __launch_bounds__(256, 2) void flash_attn(const bf16_t* __restrict__ Q,
                                                     const bf16_t* __restrict__ K,
                                                     const bf16_t* __restrict__ V,
                                                     bf16_t* __restrict__ O) {
    __shared__ bf16_t smem[2 * 64 * KP];  // sK | sVt; reused as epilogue scratch
    bf16_t* sK = smem;
    bf16_t* sVt = smem + 64 * KP;

    const int tid = threadIdx.x;
    const int wave = tid >> 6, lane = tid & 63;
    const int quad = lane >> 4, l16 = lane & 15;
    const int qt = blockIdx.y >> 1;
    const int h = blockIdx.x * 2 + (blockIdx.y & 1);  // XCD = bx -> 2 heads/XCD (KV L2-resident)
    const int b = blockIdx.z;
    const size_t base = (size_t)b * S_LEN * E_DIM + h * HD_DIM;
    const float c_exp = 0.125f * 1.44269504089f;  // scale * log2(e)

    bf16x8 qf[2][2];
#pragma unroll
    for (int mt = 0; mt < 2; mt++) {
        const bf16_t* qp =
            Q + base + (size_t)(qt * 128 + wave * 32 + mt * 16 + l16) * E_DIM + quad * 8;
        qf[mt][0] = *(const bf16x8*)qp;
        qf[mt][1] = *(const bf16x8*)(qp + 32);
    }

    float lsum[2] = {0.f, 0.f};
    f32x4 acc[2][4];
    const f32x4 vzero = {0.f, 0.f, 0.f, 0.f};
#pragma unroll
    for (int mt = 0; mt < 2; mt++)
#pragma unroll
        for (int dt = 0; dt < 4; dt++) acc[mt][dt] = vzero;

    const int stg = tid & 7;  // staging d-group (d>>3)

    for (int j0 = 0; j0 < S_LEN; j0 += 64) {
        __syncthreads();
#pragma unroll
        for (int it = 0; it < 2; it++) {
            int r = (tid >> 3) + it * 32;  // key row 0..63
            int c = stg * 8;               // d col
            bf16x8 kv = *(const bf16x8*)(K + base + (size_t)(j0 + r) * E_DIM + c);
            *(bf16x8*)&sK[r * KP + c] = kv;
            bf16x8 vv = *(const bf16x8*)(V + base + (size_t)(j0 + r) * E_DIM + c);
            int jb = (((r >> 2) ^ stg) << 2) | (r & 3);  // 4-chunk XOR, key = d>>3 = stg
#pragma unroll
            for (int i = 0; i < 8; i++) sVt[(c + i) * KP + jb] = vv[i];
        }
        __syncthreads();

        bf16x8 kf[4][2];
#pragma unroll
        for (int jt = 0; jt < 4; jt++) {
            kf[jt][0] = *(const bf16x8*)&sK[(jt * 16 + l16) * KP + quad * 8];
            kf[jt][1] = *(const bf16x8*)&sK[(jt * 16 + l16) * KP + 32 + quad * 8];
        }

        bf16x4 pb[2][4];
#pragma unroll
        for (int mt = 0; mt < 2; mt++)
#pragma unroll
            for (int jt = 0; jt < 4; jt++) {
                f32x4 s = vzero;
                s = __builtin_amdgcn_mfma_f32_16x16x32_bf16(kf[jt][0], qf[mt][0], s, 0, 0, 0);
                s = __builtin_amdgcn_mfma_f32_16x16x32_bf16(kf[jt][1], qf[mt][1], s, 0, 0, 0);
#pragma unroll
                for (int r = 0; r < 4; r++) {
                    float p = __builtin_amdgcn_exp2f(s[r] * c_exp);
                    lsum[mt] += p;
                    pb[mt][jt][r] = (bf16_t)p;
                }
            }

#pragma unroll
        for (int jt = 0; jt < 4; jt++)
#pragma unroll
            for (int dt = 0; dt < 4; dt++) {
                int cidx = (jt * 4 + quad) ^ (dt * 2 + (l16 >> 3));
                bf16x4 vf = *(const bf16x4*)&sVt[(dt * 16 + l16) * KP + cidx * 4];
#pragma unroll
                for (int mt = 0; mt < 2; mt++)
                    acc[mt][dt] = pv_mfma(vf, pb[mt][jt], acc[mt][dt]);
            }
    }

    float inv[2];
#pragma unroll
    for (int mt = 0; mt < 2; mt++) {
        lsum[mt] += __shfl_xor(lsum[mt], 16);
        lsum[mt] += __shfl_xor(lsum[mt], 32);
        inv[mt] = __builtin_amdgcn_rcpf(lsum[mt]);
    }

    __syncthreads();  // all waves done reading sK/sVt
    bf16_t* ep = smem + wave * 32 * KP;  // wave-private 32 q-rows x 72
#pragma unroll
    for (int mt = 0; mt < 2; mt++)
#pragma unroll
        for (int dt = 0; dt < 4; dt++)
#pragma unroll
            for (int r = 0; r < 4; r++)
                ep[(mt * 16 + l16) * KP + dt * 16 + quad * 4 + r] =
                    (bf16_t)(acc[mt][dt][r] * inv[mt]);
#pragma unroll
    for (int mt = 0; mt < 2; mt++)
#pragma unroll
        for (int c = 0; c < 2; c++) {
            int row = lane >> 2;
            int col = (lane & 3) * 8 + c * 32;
            bf16x8 oval = *(const bf16x8*)&ep[(mt * 16 + row) * KP + col];
            *(bf16x8*)&O[base + (size_t)(qt * 128 + wave * 32 + mt * 16 + row) * E_DIM + col] =
                oval;
        }
}

// ---------------------------------------------------------------- launch
extern "C" void kernel_launch(void* const* d_in, const int* in_sizes, int n_in,
                              void* d_out, int out_size, void* d_ws, size_t ws_size,
                              hipStream_t stream) {
    const float* q  = (const float*)d_in[0];
    const float* k  = (const float*)d_in[1];
    const float* v  = (const float*)d_in[2];
    const float* wq = (const float*)d_in[3];
    const float* wk = (const float*)d_in[4];
    const float* wv = (const float*)d_in[5];
    const float* wo = (const float*)d_in[6];
    float* out = (float*)d_out;

    const int NX = TOKENS * E_DIM;  // 4M elems

    bf16_t* ws  = (bf16_t*)d_ws;
    bf16_t* Qp  = ws;                    // 4M bf16
    bf16_t* Kp  = Qp + (size_t)NX;       // 4M
    bf16_t* Vp  = Kp + (size_t)NX;       // 4M
    bf16_t* ctx = Vp + (size_t)NX;       // 4M

    // batched projections, fp32 inputs (cast fused into staging), XCD-swizzled
    proj_gemm<<<dim3(8, 32, 3), 256, 0, stream>>>(q, k, v, wq, wk, wv, Qp, Kp, Vp);

    // attention: grid (8,16,4); h-grouped XCD swizzle inside
    flash_attn<<<dim3(8, 16, 4), 256, 0, stream>>>(Qp, Kp, Vp, ctx);

    // output projection (ctx bf16 + Wo fp32 fused-cast), XCD-swizzled -> fp32 d_out
    out_gemm<<<dim3(8, 32), 256, 0, stream>>>(ctx, wo, out);
}